// Round 11
// baseline (414.163 us; speedup 1.0000x reference)
//
#include <hip/hip_runtime.h>

// ExternalNeighbors: per-pair displacement + periodic shift + cutoff mask.
// Outputs (concatenated flat, all float32):
//   [0N..1N) dist | [1N..2N) pair_first | [2N..3N) pair_second
//   [3N..6N) paircoord (N,3) | [6N..7N) mask
//
// Ledger: v2 231us -> v3 181 (1-hop float4 table) -> v4 169 (NT st)
//   -> v5 251 REGRESS (strided NT partial lines) -> v6 153 (plain ld +
//   NT st + LDS pc transpose) -> v7 177 REGRESS (persistent loop)
//   -> v8 161 (wave_barrier) -> v9 ~144 (2x4-pair batches, 16 gathers).
// v10: v9 minus the LDS transpose -- paircoord as plain strided dwordx4
// (v3-proven exact WRITE via L2 merge), NT only on contiguous streams,
// zero LDS / zero barriers -> occupancy uncapped. Last probe: if >=140us
// the request-throughput plateau is established and we declare.

typedef float f32x4 __attribute__((ext_vector_type(4)));
typedef int   i32x4 __attribute__((ext_vector_type(4)));

#define HARD_DIST_CUTOFF 2.0f

__global__ __launch_bounds__(256) void build_gather_table(
    const float* __restrict__ coords,      // n_real * 3
    const int*   __restrict__ real_atoms,  // n_real
    f32x4* __restrict__ tab,               // n_real (padded xyz_)
    int n_real)
{
    const int i = blockIdx.x * blockDim.x + threadIdx.x;
    if (i < n_real) {
        const int a = real_atoms[i];
        const float* c = coords + 3 * (size_t)a;
        f32x4 v;
        v.x = c[0]; v.y = c[1]; v.z = c[2]; v.w = 0.0f;
        tab[i] = v;  // plain store: keep table cache-resident for the gathers
    }
}

// Requires n_pairs % 2048 == 0 (exact grid, two batches/thread, no tail).
__global__ __launch_bounds__(256) void external_neighbors_v10(
    const f32x4* __restrict__ tab,          // n_real pre-gathered coords
    const int*   __restrict__ shifts,       // n_pairs * 3
    const float* __restrict__ cell,         // 9
    const int*   __restrict__ pair_first,   // n_pairs
    const int*   __restrict__ pair_second,  // n_pairs
    float* __restrict__ out,
    int n_pairs)
{
    const float c00 = cell[0], c01 = cell[1], c02 = cell[2];
    const float c10 = cell[3], c11 = cell[4], c12 = cell[5];
    const float c20 = cell[6], c21 = cell[7], c22 = cell[8];

    const size_t N = (size_t)n_pairs;
    float* __restrict__ out_dist = out;
    float* __restrict__ out_pf   = out + N;
    float* __restrict__ out_ps   = out + 2 * N;
    float* __restrict__ out_pc   = out + 3 * N;
    float* __restrict__ out_mask = out + 6 * N;

    const int tid = blockIdx.x * blockDim.x + threadIdx.x;
    const int H   = n_pairs >> 3;              // nbatch/2 (batches of 4)

    const int bidx[2] = {tid, tid + H};

    // ---- plain (cached) coalesced loads for both batches ----
    i32x4 pf4[2], ps4[2], sA[2], sB[2], sC[2];
    #pragma unroll
    for (int j = 0; j < 2; ++j) {
        const int base = bidx[j] << 2;
        pf4[j] = *reinterpret_cast<const i32x4*>(pair_first  + base);
        ps4[j] = *reinterpret_cast<const i32x4*>(pair_second + base);
        const i32x4* sh = reinterpret_cast<const i32x4*>(shifts + 3 * (size_t)base);
        sA[j] = sh[0]; sB[j] = sh[1]; sC[j] = sh[2];
    }

    int pf[2][4], ps[2][4], s0[2][4], s1[2][4], s2[2][4];
    #pragma unroll
    for (int j = 0; j < 2; ++j) {
        pf[j][0]=pf4[j].x; pf[j][1]=pf4[j].y; pf[j][2]=pf4[j].z; pf[j][3]=pf4[j].w;
        ps[j][0]=ps4[j].x; ps[j][1]=ps4[j].y; ps[j][2]=ps4[j].z; ps[j][3]=ps4[j].w;
        s0[j][0]=sA[j].x; s0[j][1]=sA[j].w; s0[j][2]=sB[j].z; s0[j][3]=sC[j].y;
        s1[j][0]=sA[j].y; s1[j][1]=sB[j].x; s1[j][2]=sB[j].w; s1[j][3]=sC[j].z;
        s2[j][0]=sA[j].z; s2[j][1]=sB[j].y; s2[j][2]=sC[j].x; s2[j][3]=sC[j].w;
    }

    // ---- 16 independent 16B gathers (cache-resident table) ----
    f32x4 A[2][4], B[2][4];
    #pragma unroll
    for (int j = 0; j < 2; ++j) {
        #pragma unroll
        for (int k = 0; k < 4; ++k) A[j][k] = tab[pf[j][k]];
    }
    #pragma unroll
    for (int j = 0; j < 2; ++j) {
        #pragma unroll
        for (int k = 0; k < 4; ++k) B[j][k] = tab[ps[j][k]];
    }

    // ---- compute + stores, per batch ----
    #pragma unroll
    for (int j = 0; j < 2; ++j) {
        const int base = bidx[j] << 2;
        f32x4 dist, pfo, pso, msk;
        float dxv[4], dyv[4], dzv[4];
        #pragma unroll
        for (int k = 0; k < 4; ++k) {
            const float f0 = (float)s0[j][k], f1 = (float)s1[j][k], f2 = (float)s2[j][k];
            const float dx = B[j][k].x - A[j][k].x + f0 * c00 + f1 * c10 + f2 * c20;
            const float dy = B[j][k].y - A[j][k].y + f0 * c01 + f1 * c11 + f2 * c21;
            const float dz = B[j][k].z - A[j][k].z + f0 * c02 + f1 * c12 + f2 * c22;
            const float d  = sqrtf(dx * dx + dy * dy + dz * dz);
            const bool  m  = d < HARD_DIST_CUTOFF;
            dist[k] = m ? d : 0.0f;
            pfo[k]  = m ? (float)pf[j][k] : -1.0f;
            pso[k]  = m ? (float)ps[j][k] : -1.0f;
            msk[k]  = m ? 1.0f : 0.0f;
            dxv[k]  = m ? dx : 0.0f;
            dyv[k]  = m ? dy : 0.0f;
            dzv[k]  = m ? dz : 0.0f;
        }

        // NT stores on wave-contiguous streams (1KB full-line bursts)
        __builtin_nontemporal_store(dist, reinterpret_cast<f32x4*>(out_dist + base));
        __builtin_nontemporal_store(pfo,  reinterpret_cast<f32x4*>(out_pf   + base));
        __builtin_nontemporal_store(pso,  reinterpret_cast<f32x4*>(out_ps   + base));
        __builtin_nontemporal_store(msk,  reinterpret_cast<f32x4*>(out_mask + base));

        // paircoord: plain strided dwordx4 stores; L2 write-merge -> exact
        // WRITE_SIZE (proven v3: 229.6MB). Keeping these CACHED is what
        // lets L2 assemble full lines from the 48B/lane stride pattern.
        f32x4* pc = reinterpret_cast<f32x4*>(out_pc + 3 * (size_t)base);
        pc[0] = (f32x4){dxv[0], dyv[0], dzv[0], dxv[1]};
        pc[1] = (f32x4){dyv[1], dzv[1], dxv[2], dyv[2]};
        pc[2] = (f32x4){dzv[2], dxv[3], dyv[3], dzv[3]};
    }
}

// Generic fallback (any n_pairs; also used if ws too small for the table):
__global__ __launch_bounds__(256) void external_neighbors_v2(
    const float* __restrict__ coords,
    const int*   __restrict__ real_atoms,
    const int*   __restrict__ shifts,
    const float* __restrict__ cell,
    const int*   __restrict__ pair_first,
    const int*   __restrict__ pair_second,
    float* __restrict__ out,
    int n_pairs)
{
    const float c00 = cell[0], c01 = cell[1], c02 = cell[2];
    const float c10 = cell[3], c11 = cell[4], c12 = cell[5];
    const float c20 = cell[6], c21 = cell[7], c22 = cell[8];
    const size_t N = (size_t)n_pairs;
    float* out_dist = out;
    float* out_pf   = out + N;
    float* out_ps   = out + 2 * N;
    float* out_pc   = out + 3 * N;
    float* out_mask = out + 6 * N;
    const int tid = blockIdx.x * blockDim.x + threadIdx.x;
    const int stride = gridDim.x * blockDim.x;
    for (int p = tid; p < n_pairs; p += stride) {
        const int pfs = pair_first[p];
        const int pss = pair_second[p];
        const float f0 = (float)shifts[3 * p + 0];
        const float f1 = (float)shifts[3 * p + 1];
        const float f2 = (float)shifts[3 * p + 2];
        const int iaa = real_atoms[pfs];
        const int ibb = real_atoms[pss];
        const float dx = coords[3*ibb+0] - coords[3*iaa+0] + f0*c00 + f1*c10 + f2*c20;
        const float dy = coords[3*ibb+1] - coords[3*iaa+1] + f0*c01 + f1*c11 + f2*c21;
        const float dz = coords[3*ibb+2] - coords[3*iaa+2] + f0*c02 + f1*c12 + f2*c22;
        const float d  = sqrtf(dx*dx + dy*dy + dz*dz);
        const bool  m  = d < HARD_DIST_CUTOFF;
        out_dist[p] = m ? d : 0.0f;
        out_pf[p]   = m ? (float)pfs : -1.0f;
        out_ps[p]   = m ? (float)pss : -1.0f;
        out_pc[3*(size_t)p+0] = m ? dx : 0.0f;
        out_pc[3*(size_t)p+1] = m ? dy : 0.0f;
        out_pc[3*(size_t)p+2] = m ? dz : 0.0f;
        out_mask[p] = m ? 1.0f : 0.0f;
    }
}

extern "C" void kernel_launch(void* const* d_in, const int* in_sizes, int n_in,
                              void* d_out, int out_size, void* d_ws, size_t ws_size,
                              hipStream_t stream) {
    const float* coords      = (const float*)d_in[0];  // (128,1024,3) f32
    const int*   real_atoms  = (const int*)d_in[1];    // (131072,) int
    const int*   shifts      = (const int*)d_in[2];    // (8388608,3) int
    const float* cell        = (const float*)d_in[3];  // (3,3) f32
    const int*   pair_first  = (const int*)d_in[4];    // (8388608,) int
    const int*   pair_second = (const int*)d_in[5];    // (8388608,) int
    float*       out         = (float*)d_out;

    const int n_real  = in_sizes[1];  // 131072
    const int n_pairs = in_sizes[4];  // 8388608

    const size_t tab_bytes = (size_t)n_real * sizeof(f32x4);

    if (ws_size >= tab_bytes && (n_pairs % 2048) == 0) {
        f32x4* tab = (f32x4*)d_ws;
        build_gather_table<<<(n_real + 255) / 256, 256, 0, stream>>>(
            coords, real_atoms, tab, n_real);

        // 2 batches/thread: threads = n_pairs/8 -> blocks = n_pairs/2048 (4096)
        const int grid = n_pairs / 2048;
        external_neighbors_v10<<<grid, 256, 0, stream>>>(
            tab, shifts, cell, pair_first, pair_second, out, n_pairs);
    } else {
        external_neighbors_v2<<<2048, 256, 0, stream>>>(
            coords, real_atoms, shifts, cell, pair_first, pair_second, out, n_pairs);
    }
}